// Round 3
// baseline (1028.176 us; speedup 1.0000x reference)
//
#include <hip/hip_runtime.h>

#define N_NODES 500000
#define N_EDGES 8000000
#define N_GRAPHS 4096

// ---------------- binned-aggregation parameters ----------------
#define BIN_SHIFT 11
#define BIN_NODES 2048                    // 1 << BIN_SHIFT
#define NBINS 245                         // ceil(N_NODES / BIN_NODES)
#define BIN_CAP 40960                     // mean 32768, sigma ~181 -> +45 sigma
#define OVF_CAP 65536
#define P1_EPT 64
#define P1_BLOCK 256
#define P1_EDGES (P1_BLOCK * P1_EPT)      // 16384 edges per block
#define P1_GRID ((N_EDGES + P1_EDGES - 1) / P1_EDGES)   // 489
#define FXS 262144.0f                     // 2^18 fixed-point scale
#define FXI (1.0f / 262144.0f)

// ---------------- ws layout (byte offsets) ----------------
#define OFF_CURS_A   0          // 256 u32
#define OFF_CURS_B   1024
#define OFF_OVFC_A   2048       // u32 (padded)
#define OFF_OVFC_B   2304
#define ZERO_SMALL   2560       // zero [0, ZERO_SMALL) per call (binned path)
#define OFF_STARTS_A 4096       // 4097 u32 (padded to 16640)
#define OFF_STARTS_B 20736
#define OFF_MEAN_A   37376      // 12288 f32
#define OFF_MEAN_B   86528
#define OFF_OVF_A    135680     // 65536 x float4
#define OFF_OVF_B    1184256
#define OFF_AGGF_A   2232832    // 1,000,000 f32
#define OFF_AGGF_B   6232832
#define OFF_BINS     10232832   // NBINS*BIN_CAP u64 = 80,281,600
#define WS_NEED (OFF_BINS + (size_t)NBINS * BIN_CAP * 8)  // 90,514,432

// ===========================================================================
// Pass 1: per-block LDS histogram of dst bins -> one global cursor
// reservation per (block,bin) [~120K returning atomics vs 8M in R2] ->
// compute m, pack (local:11|fx0:26|fx1:26) u64, scattered 8B store into the
// bin region (L2 write-back makes HBM cost ~dense 64 MB).
// ===========================================================================
__global__ __launch_bounds__(256) void p1_kernel(
    const float* __restrict__ x, const int* __restrict__ ei,
    const float* __restrict__ ea,
    const float* __restrict__ Wf, const float* __restrict__ bfv,
    const float* __restrict__ Ws, const float* __restrict__ bsv,
    unsigned long long* __restrict__ bins, unsigned int* __restrict__ cursors,
    unsigned int* __restrict__ ovf_cnt, float4* __restrict__ ovf)
{
    __shared__ unsigned int hist[NBINS];
    float wf[12], ws[12];
#pragma unroll
    for (int i = 0; i < 12; ++i) { wf[i] = Wf[i]; ws[i] = Ws[i]; }
    float bf0 = bfv[0], bf1 = bfv[1], bs0 = bsv[0], bs1 = bsv[1];

    int t = threadIdx.x;
    int ebase = blockIdx.x * P1_EDGES;

    for (int i = t; i < NBINS; i += 256) hist[i] = 0;
    __syncthreads();

    // histogram of dst bins (reads dst only)
    for (int i = 0; i < P1_EPT; ++i) {
        int e = ebase + i * 256 + t;
        if (e >= N_EDGES) break;
        atomicAdd(&hist[(unsigned)ei[N_EDGES + e] >> BIN_SHIFT], 1u);
    }
    __syncthreads();

    // reserve contiguous per-bin ranges; hist becomes the block-local cursor
    for (int i = t; i < NBINS; i += 256) {
        unsigned c = hist[i];
        hist[i] = c ? atomicAdd(&cursors[i], c) : 0u;
    }
    __syncthreads();

    // compute messages and scatter into bins
    for (int i = 0; i < P1_EPT; ++i) {
        int e = ebase + i * 256 + t;
        if (e >= N_EDGES) break;
        int src = ei[e];
        int dst = ei[N_EDGES + e];
        float2 xd = ((const float2*)x)[dst];
        float2 xs = ((const float2*)x)[src];
        float2 ev = ((const float2*)ea)[e];
        float z0 = xd.x, z1 = xd.y, z2 = xs.x, z3 = xs.y, z4 = ev.x, z5 = ev.y;

        float f0 = bf0 + z0*wf[0] + z1*wf[2] + z2*wf[4] + z3*wf[6] + z4*wf[8]  + z5*wf[10];
        float f1 = bf1 + z0*wf[1] + z1*wf[3] + z2*wf[5] + z3*wf[7] + z4*wf[9]  + z5*wf[11];
        float s0 = bs0 + z0*ws[0] + z1*ws[2] + z2*ws[4] + z3*ws[6] + z4*ws[8]  + z5*ws[10];
        float s1 = bs1 + z0*ws[1] + z1*ws[3] + z2*ws[5] + z3*ws[7] + z4*ws[9]  + z5*ws[11];

        float m0 = (1.f/(1.f+__expf(-f0))) * (fmaxf(s0,0.f) + __logf(1.f+__expf(-fabsf(s0))));
        float m1 = (1.f/(1.f+__expf(-f1))) * (fmaxf(s1,0.f) + __logf(1.f+__expf(-fabsf(s1))));

        int b = (int)((unsigned)dst >> BIN_SHIFT);
        bool pk_ok = (m0 < 255.0f) && (m1 < 255.0f);   // 26-bit field bound
        unsigned idx = 0xFFFFFFFFu;
        if (pk_ok) idx = atomicAdd(&hist[b], 1u);
        if (pk_ok && idx < BIN_CAP) {
            unsigned fx0 = __float2uint_rn(m0 * FXS);
            unsigned fx1 = __float2uint_rn(m1 * FXS);
            bins[(size_t)b * BIN_CAP + idx] =
                  (unsigned long long)((unsigned)dst & (BIN_NODES - 1))
                | ((unsigned long long)fx0 << 11)
                | ((unsigned long long)fx1 << 37);
        } else {
            unsigned oi = atomicAdd(ovf_cnt, 1u);
            if (oi < OVF_CAP) ovf[oi] = make_float4(__int_as_float(dst), m0, m1, 0.f);
        }
    }
}

// ===========================================================================
// Pass 2: one block per bin; LDS f32 atomics accumulate the bin's edges into
// a 16 KB node slice; coalesced plain stores write the slice to aggf.
// ===========================================================================
__global__ __launch_bounds__(512) void p2_kernel(
    const unsigned long long* __restrict__ bins,
    const unsigned int* __restrict__ cursors,
    float* __restrict__ aggf)
{
    __shared__ float acc[BIN_NODES * 2];
    int b = blockIdx.x, t = threadIdx.x;
    for (int i = t; i < BIN_NODES * 2; i += 512) acc[i] = 0.f;
    __syncthreads();

    int n = (int)min(cursors[b], (unsigned)BIN_CAP);
    const unsigned long long* bp = bins + (size_t)b * BIN_CAP;
    for (int i = t; i < n; i += 512) {
        unsigned long long v = bp[i];
        int local = (int)(v & (BIN_NODES - 1));
        float m0 = (float)((unsigned)(v >> 11) & 0x03FFFFFFu) * FXI;
        float m1 = (float)((unsigned)(v >> 37)) * FXI;
        atomicAdd(&acc[2 * local],     m0);
        atomicAdd(&acc[2 * local + 1], m1);
    }
    __syncthreads();

    int node0 = b * BIN_NODES;
    for (int i = t; i < BIN_NODES; i += 512) {
        int node = node0 + i;
        if (node < N_NODES)
            ((float2*)aggf)[node] = make_float2(acc[2 * i], acc[2 * i + 1]);
    }
}

// Replay overflow edges (statistically never occurs; correctness guard).
__global__ __launch_bounds__(256) void ovf_kernel(
    const float4* __restrict__ ovf, const unsigned int* __restrict__ ovf_cnt,
    float* __restrict__ aggf)
{
    int n = (int)min(*ovf_cnt, (unsigned)OVF_CAP);
    for (int i = threadIdx.x; i < n; i += 256) {
        float4 r = ovf[i];
        int dst = __float_as_int(r.x);
        unsafeAtomicAdd(&aggf[2 * dst],     r.y);
        unsafeAtomicAdd(&aggf[2 * dst + 1], r.z);
    }
}

// ===========================================================================
// Segment boundaries of the sorted batch array -> starts[0..N_GRAPHS].
// Removes the 19-step dependent binary search from the pool kernel.
// ===========================================================================
__global__ __launch_bounds__(256) void starts_kernel(
    const int* __restrict__ batch, unsigned int* __restrict__ starts)
{
    int i = blockIdx.x * 256 + threadIdx.x;
    if (i >= N_NODES) return;
    int b1 = batch[i];
    if (i == 0) {
        for (int g = 0; g <= b1; ++g) starts[g] = 0;
    } else {
        int b0 = batch[i - 1];
        for (int g = b0 + 1; g <= b1; ++g) starts[g] = i;
    }
    if (i == N_NODES - 1) {
        for (int g = b1 + 1; g <= N_GRAPHS; ++g) starts[g] = N_NODES;
    }
}

// Pool: 4 graphs per 256-thread block (one wave each).
__global__ __launch_bounds__(256) void pool2_kernel(
    const float* __restrict__ x, const float* __restrict__ aggf,
    const unsigned int* __restrict__ starts,
    const float* __restrict__ W1, const float* __restrict__ b1,
    float* __restrict__ mean_out)
{
    int wave = threadIdx.x >> 6, lane = threadIdx.x & 63;
    int g = blockIdx.x * 4 + wave;

    float w00 = W1[0], w01 = W1[1], w02 = W1[2];
    float w10 = W1[3], w11 = W1[4], w12 = W1[5];
    float c0 = b1[0], c1 = b1[1], c2 = b1[2];

    int s = (int)starts[g], e = (int)starts[g + 1];
    float a0 = 0.f, a1 = 0.f, a2 = 0.f;
    for (int i = s + lane; i < e; i += 64) {
        float2 xv = ((const float2*)x)[i];
        float2 gv = ((const float2*)aggf)[i];
        float h0 = xv.x + gv.x;
        float h1 = xv.y + gv.y;
        a0 += fmaxf(h0*w00 + h1*w10 + c0, 0.f);
        a1 += fmaxf(h0*w01 + h1*w11 + c1, 0.f);
        a2 += fmaxf(h0*w02 + h1*w12 + c2, 0.f);
    }
#pragma unroll
    for (int off = 32; off; off >>= 1) {
        a0 += __shfl_down(a0, off);
        a1 += __shfl_down(a1, off);
        a2 += __shfl_down(a2, off);
    }
    if (lane == 0) {
        float inv = 1.0f / fmaxf((float)(e - s), 1.0f);
        mean_out[3*(size_t)g]     = a0 * inv;
        mean_out[3*(size_t)g + 1] = a1 * inv;
        mean_out[3*(size_t)g + 2] = a2 * inv;
    }
}

// Final MLP + MSE loss (single block).
__global__ __launch_bounds__(1024) void final_kernel(
    const float* __restrict__ ma, const float* __restrict__ mb,
    const float* __restrict__ W2, const float* __restrict__ b2,
    const float* __restrict__ targets,
    float* __restrict__ out)
{
    __shared__ float red[1024];
    float w0 = W2[0], w1 = W2[1], w2 = W2[2], w3 = W2[3], w4 = W2[4], w5 = W2[5];
    float bias = b2[0];

    float lsum = 0.f;
    for (int g = threadIdx.x; g < N_GRAPHS; g += 1024) {
        float v = bias
                + ma[3*(size_t)g]*w0 + ma[3*(size_t)g+1]*w1 + ma[3*(size_t)g+2]*w2
                + mb[3*(size_t)g]*w3 + mb[3*(size_t)g+1]*w4 + mb[3*(size_t)g+2]*w5;
        v = fmaxf(v, 0.f);
        out[g] = v;
        float d = v - targets[g];
        lsum += d * d;
    }
    red[threadIdx.x] = lsum;
    __syncthreads();
#pragma unroll
    for (int off = 512; off; off >>= 1) {
        if (threadIdx.x < (unsigned)off) red[threadIdx.x] += red[threadIdx.x + off];
        __syncthreads();
    }
    if (threadIdx.x == 0) out[N_GRAPHS] = red[0] * (1.0f / (float)N_GRAPHS);
}

// ===========================================================================
// Fallback path (ws too small): R2's u64-packed global-atomic kernel.
// ===========================================================================
#define FB_SCALE 4194304.0f
#define FB_INV   2.384185791015625e-07f

__global__ __launch_bounds__(256) void fb_edge_kernel(
    const float* __restrict__ x, const int* __restrict__ ei,
    const float* __restrict__ ea,
    const float* __restrict__ Wf, const float* __restrict__ bfv,
    const float* __restrict__ Ws, const float* __restrict__ bsv,
    unsigned long long* __restrict__ agg)
{
    float wf[12], ws[12];
#pragma unroll
    for (int i = 0; i < 12; ++i) { wf[i] = Wf[i]; ws[i] = Ws[i]; }
    float bf0 = bfv[0], bf1 = bfv[1], bs0 = bsv[0], bs1 = bsv[1];

    int e = blockIdx.x * 256 + threadIdx.x;
    int src = ei[e];
    int dst = ei[N_EDGES + e];
    float2 xd = ((const float2*)x)[dst];
    float2 xs = ((const float2*)x)[src];
    float2 ev = ((const float2*)ea)[e];
    float z0 = xd.x, z1 = xd.y, z2 = xs.x, z3 = xs.y, z4 = ev.x, z5 = ev.y;

    float f0 = bf0 + z0*wf[0] + z1*wf[2] + z2*wf[4] + z3*wf[6] + z4*wf[8]  + z5*wf[10];
    float f1 = bf1 + z0*wf[1] + z1*wf[3] + z2*wf[5] + z3*wf[7] + z4*wf[9]  + z5*wf[11];
    float s0 = bs0 + z0*ws[0] + z1*ws[2] + z2*ws[4] + z3*ws[6] + z4*ws[8]  + z5*ws[10];
    float s1 = bs1 + z0*ws[1] + z1*ws[3] + z2*ws[5] + z3*ws[7] + z4*ws[9]  + z5*ws[11];

    float m0 = (1.f/(1.f+__expf(-f0))) * (fmaxf(s0,0.f) + __logf(1.f+__expf(-fabsf(s0))));
    float m1 = (1.f/(1.f+__expf(-f1))) * (fmaxf(s1,0.f) + __logf(1.f+__expf(-fabsf(s1))));

    unsigned int fx0 = __float2uint_rn(m0 * FB_SCALE);
    unsigned int fx1 = __float2uint_rn(m1 * FB_SCALE);
    atomicAdd(&agg[dst], (unsigned long long)fx0 | ((unsigned long long)fx1 << 32));
}

__global__ __launch_bounds__(64) void fb_pool_kernel(
    const float* __restrict__ x, const unsigned long long* __restrict__ agg,
    const int* __restrict__ batch,
    const float* __restrict__ W1, const float* __restrict__ b1,
    float* __restrict__ mean_out)
{
    int b = blockIdx.x;
    float w00 = W1[0], w01 = W1[1], w02 = W1[2];
    float w10 = W1[3], w11 = W1[4], w12 = W1[5];
    float c0 = b1[0], c1 = b1[1], c2 = b1[2];

    int lo = 0, hi = N_NODES;
    while (lo < hi) { int mid = (lo + hi) >> 1; if (batch[mid] < b) lo = mid + 1; else hi = mid; }
    int seg_s = lo;
    hi = N_NODES;
    while (lo < hi) { int mid = (lo + hi) >> 1; if (batch[mid] < b + 1) lo = mid + 1; else hi = mid; }
    int seg_e = lo;

    float a0 = 0.f, a1 = 0.f, a2 = 0.f;
    for (int i = seg_s + (int)threadIdx.x; i < seg_e; i += 64) {
        unsigned long long v = agg[i];
        float g0 = (float)(unsigned int)(v & 0xffffffffull) * FB_INV;
        float g1 = (float)(unsigned int)(v >> 32) * FB_INV;
        float2 xv = ((const float2*)x)[i];
        float h0 = xv.x + g0, h1 = xv.y + g1;
        a0 += fmaxf(h0*w00 + h1*w10 + c0, 0.f);
        a1 += fmaxf(h0*w01 + h1*w11 + c1, 0.f);
        a2 += fmaxf(h0*w02 + h1*w12 + c2, 0.f);
    }
#pragma unroll
    for (int off = 32; off; off >>= 1) {
        a0 += __shfl_down(a0, off);
        a1 += __shfl_down(a1, off);
        a2 += __shfl_down(a2, off);
    }
    if (threadIdx.x == 0) {
        float inv = 1.0f / fmaxf((float)(seg_e - seg_s), 1.0f);
        mean_out[3*(size_t)b]     = a0 * inv;
        mean_out[3*(size_t)b + 1] = a1 * inv;
        mean_out[3*(size_t)b + 2] = a2 * inv;
    }
}

extern "C" void kernel_launch(void* const* d_in, const int* in_sizes, int n_in,
                              void* d_out, int out_size, void* d_ws, size_t ws_size,
                              hipStream_t stream) {
    const float* x_a     = (const float*)d_in[0];
    const int*   ei_a    = (const int*)  d_in[1];
    const float* ea_a    = (const float*)d_in[2];
    const int*   batch_a = (const int*)  d_in[3];
    const float* x_b     = (const float*)d_in[4];
    const int*   ei_b    = (const int*)  d_in[5];
    const float* ea_b    = (const float*)d_in[6];
    const int*   batch_b = (const int*)  d_in[7];
    const float* targets = (const float*)d_in[8];
    const float* Wf = (const float*)d_in[10];
    const float* bf = (const float*)d_in[11];
    const float* Ws = (const float*)d_in[12];
    const float* bs = (const float*)d_in[13];
    const float* W1 = (const float*)d_in[14];
    const float* b1 = (const float*)d_in[15];
    const float* W2 = (const float*)d_in[16];
    const float* b2 = (const float*)d_in[17];
    float* out = (float*)d_out;
    char* ws = (char*)d_ws;

    if (ws_size >= WS_NEED) {
        unsigned int* curs_a   = (unsigned int*)(ws + OFF_CURS_A);
        unsigned int* curs_b   = (unsigned int*)(ws + OFF_CURS_B);
        unsigned int* ovfc_a   = (unsigned int*)(ws + OFF_OVFC_A);
        unsigned int* ovfc_b   = (unsigned int*)(ws + OFF_OVFC_B);
        unsigned int* starts_a = (unsigned int*)(ws + OFF_STARTS_A);
        unsigned int* starts_b = (unsigned int*)(ws + OFF_STARTS_B);
        float* mean_a = (float*)(ws + OFF_MEAN_A);
        float* mean_b = (float*)(ws + OFF_MEAN_B);
        float4* ovf_a = (float4*)(ws + OFF_OVF_A);
        float4* ovf_b = (float4*)(ws + OFF_OVF_B);
        float* aggf_a = (float*)(ws + OFF_AGGF_A);
        float* aggf_b = (float*)(ws + OFF_AGGF_B);
        unsigned long long* bins = (unsigned long long*)(ws + OFF_BINS);

        hipMemsetAsync(ws, 0, ZERO_SMALL, stream);

        int sgrid = (N_NODES + 255) / 256;
        starts_kernel<<<sgrid, 256, 0, stream>>>(batch_a, starts_a);
        starts_kernel<<<sgrid, 256, 0, stream>>>(batch_b, starts_b);

        p1_kernel<<<P1_GRID, P1_BLOCK, 0, stream>>>(x_a, ei_a, ea_a, Wf, bf, Ws, bs,
                                                    bins, curs_a, ovfc_a, ovf_a);
        p2_kernel<<<NBINS, 512, 0, stream>>>(bins, curs_a, aggf_a);
        ovf_kernel<<<1, 256, 0, stream>>>(ovf_a, ovfc_a, aggf_a);

        p1_kernel<<<P1_GRID, P1_BLOCK, 0, stream>>>(x_b, ei_b, ea_b, Wf, bf, Ws, bs,
                                                    bins, curs_b, ovfc_b, ovf_b);
        p2_kernel<<<NBINS, 512, 0, stream>>>(bins, curs_b, aggf_b);
        ovf_kernel<<<1, 256, 0, stream>>>(ovf_b, ovfc_b, aggf_b);

        pool2_kernel<<<N_GRAPHS / 4, 256, 0, stream>>>(x_a, aggf_a, starts_a, W1, b1, mean_a);
        pool2_kernel<<<N_GRAPHS / 4, 256, 0, stream>>>(x_b, aggf_b, starts_b, W1, b1, mean_b);

        final_kernel<<<1, 1024, 0, stream>>>(mean_a, mean_b, W2, b2, targets, out);
    } else {
        // Fallback: R2 path (u64 packed global atomics), needs ~8.1 MB ws.
        unsigned long long* aggu_a = (unsigned long long*)ws;
        unsigned long long* aggu_b = aggu_a + (size_t)N_NODES;
        float* mean_a = (float*)(aggu_b + (size_t)N_NODES);
        float* mean_b = mean_a + 3 * (size_t)N_GRAPHS;

        hipMemsetAsync(ws, 0, 2 * (size_t)N_NODES * sizeof(unsigned long long), stream);
        fb_edge_kernel<<<N_EDGES / 256, 256, 0, stream>>>(x_a, ei_a, ea_a, Wf, bf, Ws, bs, aggu_a);
        fb_edge_kernel<<<N_EDGES / 256, 256, 0, stream>>>(x_b, ei_b, ea_b, Wf, bf, Ws, bs, aggu_b);
        fb_pool_kernel<<<N_GRAPHS, 64, 0, stream>>>(x_a, aggu_a, batch_a, W1, b1, mean_a);
        fb_pool_kernel<<<N_GRAPHS, 64, 0, stream>>>(x_b, aggu_b, batch_b, W1, b1, mean_b);
        final_kernel<<<1, 1024, 0, stream>>>(mean_a, mean_b, W2, b2, targets, out);
    }
}